// Round 1
// baseline (2803.309 us; speedup 1.0000x reference)
//
#include <hip/hip_runtime.h>
#include <math.h>

#define N_NODES 50000
#define N_EDGES 800000
#define HIDDEN  256
#define OUT_DIM 10
#define LN_EPS  1e-5f

// ---------------------------------------------------------------- degree ----
__global__ __launch_bounds__(256) void deg_kernel(const int* __restrict__ dst,
                                                  float* __restrict__ deg, int E) {
    int i = blockIdx.x * blockDim.x + threadIdx.x;
    int stride = gridDim.x * blockDim.x;
    for (; i < E; i += stride) {
        atomicAdd(&deg[dst[i]], 1.0f);
    }
}

// deg -> dinv in place (self-loop adds 1 to every degree; deg+1 >= 1 always)
__global__ __launch_bounds__(256) void dinv_kernel(float* __restrict__ deg, int N) {
    int i = blockIdx.x * blockDim.x + threadIdx.x;
    if (i < N) deg[i] = rsqrtf(deg[i] + 1.0f);
}

// ------------------------------------------------------------ edge scatter ----
// One wave (64 lanes) per edge; lane owns 4 contiguous columns.
// h[src] is recomputed from nf[src] (2 floats) instead of gathered (1KB).
__global__ __launch_bounds__(256) void scatter_kernel(const int* __restrict__ src,
                                                      const int* __restrict__ dst,
                                                      const float* __restrict__ nf,
                                                      const float* __restrict__ Wg,
                                                      const float* __restrict__ dinv,
                                                      float* __restrict__ agg, int E) {
    const int lane  = threadIdx.x & 63;
    const int gwave = (blockIdx.x * blockDim.x + threadIdx.x) >> 6;
    const int nwave = (gridDim.x * blockDim.x) >> 6;

    // Per-lane slice of W_gcn rows (fixed columns lane*4 .. lane*4+3)
    const float4 w0 = *reinterpret_cast<const float4*>(&Wg[lane * 4]);
    const float4 w1 = *reinterpret_cast<const float4*>(&Wg[HIDDEN + lane * 4]);

    for (int e = gwave; e < E; e += nwave) {
        const int s = src[e];
        const int d = dst[e];
        const float norm = dinv[s] * dinv[d];
        const float x0 = nf[2 * s] * norm;
        const float x1 = nf[2 * s + 1] * norm;
        float* out = &agg[(size_t)d * HIDDEN + lane * 4];
        atomicAdd(out + 0, x0 * w0.x + x1 * w1.x);
        atomicAdd(out + 1, x0 * w0.y + x1 * w1.y);
        atomicAdd(out + 2, x0 * w0.z + x1 * w1.z);
        atomicAdd(out + 3, x0 * w0.w + x1 * w1.w);
    }
}

// --------------------------------------- bias + relu + layernorm + pool ----
// One 256-thread block per node (grid-stride). Self-loop term recomputed here.
__global__ __launch_bounds__(256) void ln_pool_kernel(const float* __restrict__ agg,
                                                      const float* __restrict__ nf,
                                                      const float* __restrict__ Wg,
                                                      const float* __restrict__ dinv,
                                                      const float* __restrict__ bg,
                                                      const float* __restrict__ gamma,
                                                      const float* __restrict__ beta,
                                                      float* __restrict__ pooled, int N) {
    const int j    = threadIdx.x;
    const int wave = j >> 6;
    const int lane = j & 63;
    __shared__ float s_sum[4], s_sq[4];
    __shared__ float s_mu, s_rstd;

    const float w0j = Wg[j];
    const float w1j = Wg[HIDDEN + j];
    const float bgj = bg[j];
    const float gj  = gamma[j];
    const float bj  = beta[j];

    float acc = 0.0f;
    for (int n = blockIdx.x; n < N; n += gridDim.x) {
        const float di = dinv[n];
        const float x0 = nf[2 * n];
        const float x1 = nf[2 * n + 1];
        float v = agg[(size_t)n * HIDDEN + j] + (x0 * w0j + x1 * w1j) * di * di + bgj;
        v = fmaxf(v, 0.0f);

        float s = v, q = v * v;
        for (int o = 32; o; o >>= 1) {
            s += __shfl_down(s, o, 64);
            q += __shfl_down(q, o, 64);
        }
        if (lane == 0) { s_sum[wave] = s; s_sq[wave] = q; }
        __syncthreads();
        if (j == 0) {
            const float ts = s_sum[0] + s_sum[1] + s_sum[2] + s_sum[3];
            const float tq = s_sq[0] + s_sq[1] + s_sq[2] + s_sq[3];
            const float mu = ts * (1.0f / HIDDEN);
            const float var = tq * (1.0f / HIDDEN) - mu * mu;
            s_mu = mu;
            s_rstd = rsqrtf(var + LN_EPS);
        }
        __syncthreads();
        acc += (v - s_mu) * s_rstd * gj + bj;
    }
    atomicAdd(&pooled[j], acc);
}

// ------------------------------------------------------------- MLP head ----
__global__ __launch_bounds__(256) void mlp_kernel(const float* __restrict__ pooled,
                                                  const float* __restrict__ Wh,
                                                  const float* __restrict__ bh,
                                                  const float* __restrict__ Wo,
                                                  const float* __restrict__ bo,
                                                  float* __restrict__ out) {
    __shared__ float p[HIDDEN], z[HIDDEN], logits[OUT_DIM];
    const int j = threadIdx.x;
    p[j] = pooled[j];
    __syncthreads();

    float s = bh[j];
    for (int k = 0; k < HIDDEN; ++k) s += p[k] * Wh[k * HIDDEN + j];
    z[j] = fmaxf(s, 0.0f);
    __syncthreads();

    if (j < OUT_DIM) {
        float t = bo[j];
        for (int k = 0; k < HIDDEN; ++k) t += z[k] * Wo[k * OUT_DIM + j];
        logits[j] = t;
    }
    __syncthreads();

    if (j == 0) {
        float m = logits[0];
        for (int k = 1; k < OUT_DIM; ++k) m = fmaxf(m, logits[k]);
        float sum = 0.0f;
        for (int k = 0; k < OUT_DIM; ++k) sum += expf(logits[k] - m);
        const float lse = m + logf(sum);
        for (int k = 0; k < OUT_DIM; ++k) out[k] = logits[k] - lse;
    }
}

// ---------------------------------------------------------------- launch ----
extern "C" void kernel_launch(void* const* d_in, const int* in_sizes, int n_in,
                              void* d_out, int out_size, void* d_ws, size_t ws_size,
                              hipStream_t stream) {
    const float* nf    = (const float*)d_in[0];   // [N, 2]
    const int*   ei    = (const int*)  d_in[1];   // [2, E] (int32 under jax x32)
    const float* Wg    = (const float*)d_in[2];   // [2, H]
    const float* bg    = (const float*)d_in[3];   // [H]
    const float* gamma = (const float*)d_in[4];   // [H]
    const float* beta  = (const float*)d_in[5];   // [H]
    const float* Wh    = (const float*)d_in[6];   // [H, H]
    const float* bh    = (const float*)d_in[7];   // [H]
    const float* Wo    = (const float*)d_in[8];   // [H, OUT]
    const float* bo    = (const float*)d_in[9];   // [OUT]
    float* out = (float*)d_out;

    const int* srcp = ei;
    const int* dstp = ei + N_EDGES;

    // workspace layout
    float* agg    = (float*)d_ws;                       // N*H floats (51.2 MB)
    float* dinv   = agg + (size_t)N_NODES * HIDDEN;     // N floats (deg first, then dinv)
    float* pooled = dinv + N_NODES;                     // H floats

    hipMemsetAsync(agg, 0, (size_t)N_NODES * HIDDEN * sizeof(float), stream);
    hipMemsetAsync(dinv, 0, N_NODES * sizeof(float), stream);
    hipMemsetAsync(pooled, 0, HIDDEN * sizeof(float), stream);

    deg_kernel<<<2048, 256, 0, stream>>>(dstp, dinv, N_EDGES);
    dinv_kernel<<<(N_NODES + 255) / 256, 256, 0, stream>>>(dinv, N_NODES);
    scatter_kernel<<<2048, 256, 0, stream>>>(srcp, dstp, nf, Wg, dinv, agg, N_EDGES);
    ln_pool_kernel<<<2048, 256, 0, stream>>>(agg, nf, Wg, dinv, bg, gamma, beta, pooled, N_NODES);
    mlp_kernel<<<1, 256, 0, stream>>>(pooled, Wh, bh, Wo, bo, out);
}

// Round 2
// 186.074 us; speedup vs baseline: 15.0655x; 15.0655x over previous
//
#include <hip/hip_runtime.h>
#include <math.h>

#define N_NODES 50000
#define N_EDGES 800000
#define HIDDEN  256
#define OUT_DIM 10
#define LN_EPS  1e-5f

// ---------------------------------------------------------------- degree ----
__global__ __launch_bounds__(256) void deg_kernel(const int* __restrict__ dst,
                                                  float* __restrict__ deg, int E) {
    int i = blockIdx.x * blockDim.x + threadIdx.x;
    if (i < E) atomicAdd(&deg[dst[i]], 1.0f);
}

// deg -> dinv in place (self-loop adds 1 to every degree; deg+1 >= 1 always)
__global__ __launch_bounds__(256) void dinv_kernel(float* __restrict__ deg, int N) {
    int i = blockIdx.x * blockDim.x + threadIdx.x;
    if (i < N) deg[i] = rsqrtf(deg[i] + 1.0f);
}

// ------------------------------------------------------------ edge scatter ----
// Key algebraic identity (d_in == 2): the GCN linear commutes with the sum,
// so per destination we only accumulate TWO scalars:
//   S0[d] = sum_e norm_e * x0[src_e],  S1[d] = sum_e norm_e * x1[src_e]
// 1.6M atomics instead of 204.8M; agg[N][H] never materialized.
__global__ __launch_bounds__(256) void scatter2_kernel(const int* __restrict__ src,
                                                       const int* __restrict__ dst,
                                                       const float2* __restrict__ nf,
                                                       const float* __restrict__ dinv,
                                                       float* __restrict__ S, int E) {
    int e = blockIdx.x * blockDim.x + threadIdx.x;
    if (e >= E) return;
    const int s = src[e];
    const int d = dst[e];
    const float norm = dinv[s] * dinv[d];
    const float2 x = nf[s];
    atomicAdd(&S[2 * d],     norm * x.x);
    atomicAdd(&S[2 * d + 1], norm * x.y);
}

// --------------------------------------- GCN expand + relu + LN + pool ----
// Wave-per-node: lane owns 4 contiguous columns (W rows in registers),
// __shfl_xor reduction for mean/var, no block barriers in the node loop.
// Self-loop term (dinv[n]^2 * x[n]) added here.
__global__ __launch_bounds__(256) void ln_pool_kernel(const float2* __restrict__ nf,
                                                      const float* __restrict__ Wg,
                                                      const float* __restrict__ dinv,
                                                      const float* __restrict__ S,
                                                      const float* __restrict__ bg,
                                                      const float* __restrict__ gamma,
                                                      const float* __restrict__ beta,
                                                      float* __restrict__ pooled, int N) {
    const int tid  = threadIdx.x;
    const int lane = tid & 63;
    const int wv   = tid >> 6;
    const int gw   = (blockIdx.x * blockDim.x + tid) >> 6;
    const int nw   = (gridDim.x * blockDim.x) >> 6;

    const float4 w0  = *reinterpret_cast<const float4*>(&Wg[lane * 4]);
    const float4 w1  = *reinterpret_cast<const float4*>(&Wg[HIDDEN + lane * 4]);
    const float4 bgv = *reinterpret_cast<const float4*>(&bg[lane * 4]);
    const float4 gv  = *reinterpret_cast<const float4*>(&gamma[lane * 4]);
    const float4 bv  = *reinterpret_cast<const float4*>(&beta[lane * 4]);

    float a0 = 0.f, a1 = 0.f, a2 = 0.f, a3 = 0.f;

    for (int n = gw; n < N; n += nw) {
        const float di = dinv[n];
        const float2 x = nf[n];
        const float dd = di * di;
        const float s0 = S[2 * n]     + dd * x.x;
        const float s1 = S[2 * n + 1] + dd * x.y;

        float v0 = fmaxf(fmaf(s1, w1.x, fmaf(s0, w0.x, bgv.x)), 0.f);
        float v1 = fmaxf(fmaf(s1, w1.y, fmaf(s0, w0.y, bgv.y)), 0.f);
        float v2 = fmaxf(fmaf(s1, w1.z, fmaf(s0, w0.z, bgv.z)), 0.f);
        float v3 = fmaxf(fmaf(s1, w1.w, fmaf(s0, w0.w, bgv.w)), 0.f);

        float sum = v0 + v1 + v2 + v3;
        float sq  = v0 * v0 + v1 * v1 + v2 * v2 + v3 * v3;
        #pragma unroll
        for (int o = 1; o < 64; o <<= 1) {
            sum += __shfl_xor(sum, o, 64);
            sq  += __shfl_xor(sq,  o, 64);
        }
        const float mu   = sum * (1.0f / HIDDEN);
        const float var  = sq * (1.0f / HIDDEN) - mu * mu;
        const float rstd = rsqrtf(var + LN_EPS);

        a0 += (v0 - mu) * rstd * gv.x + bv.x;
        a1 += (v1 - mu) * rstd * gv.y + bv.y;
        a2 += (v2 - mu) * rstd * gv.z + bv.z;
        a3 += (v3 - mu) * rstd * gv.w + bv.w;
    }

    // block-level reduce (4 waves) then one atomic per column per block
    __shared__ float lds[4][HIDDEN];
    lds[wv][lane * 4 + 0] = a0;
    lds[wv][lane * 4 + 1] = a1;
    lds[wv][lane * 4 + 2] = a2;
    lds[wv][lane * 4 + 3] = a3;
    __syncthreads();
    const float t = lds[0][tid] + lds[1][tid] + lds[2][tid] + lds[3][tid];
    atomicAdd(&pooled[tid], t);
}

// ------------------------------------------------------------- MLP head ----
__global__ __launch_bounds__(256) void mlp_kernel(const float* __restrict__ pooled,
                                                  const float* __restrict__ Wh,
                                                  const float* __restrict__ bh,
                                                  const float* __restrict__ Wo,
                                                  const float* __restrict__ bo,
                                                  float* __restrict__ out) {
    __shared__ float p[HIDDEN], z[HIDDEN], logits[OUT_DIM];
    const int j = threadIdx.x;
    p[j] = pooled[j];
    __syncthreads();

    float s = bh[j];
    for (int k = 0; k < HIDDEN; ++k) s += p[k] * Wh[k * HIDDEN + j];
    z[j] = fmaxf(s, 0.0f);
    __syncthreads();

    if (j < OUT_DIM) {
        float t = bo[j];
        for (int k = 0; k < HIDDEN; ++k) t += z[k] * Wo[k * OUT_DIM + j];
        logits[j] = t;
    }
    __syncthreads();

    if (j == 0) {
        float m = logits[0];
        for (int k = 1; k < OUT_DIM; ++k) m = fmaxf(m, logits[k]);
        float sum = 0.0f;
        for (int k = 0; k < OUT_DIM; ++k) sum += expf(logits[k] - m);
        const float lse = m + logf(sum);
        for (int k = 0; k < OUT_DIM; ++k) out[k] = logits[k] - lse;
    }
}

// ---------------------------------------------------------------- launch ----
extern "C" void kernel_launch(void* const* d_in, const int* in_sizes, int n_in,
                              void* d_out, int out_size, void* d_ws, size_t ws_size,
                              hipStream_t stream) {
    const float* nf    = (const float*)d_in[0];   // [N, 2]
    const int*   ei    = (const int*)  d_in[1];   // [2, E] (int32 under jax x32)
    const float* Wg    = (const float*)d_in[2];   // [2, H]
    const float* bg    = (const float*)d_in[3];   // [H]
    const float* gamma = (const float*)d_in[4];   // [H]
    const float* beta  = (const float*)d_in[5];   // [H]
    const float* Wh    = (const float*)d_in[6];   // [H, H]
    const float* bh    = (const float*)d_in[7];   // [H]
    const float* Wo    = (const float*)d_in[8];   // [H, OUT]
    const float* bo    = (const float*)d_in[9];   // [OUT]
    float* out = (float*)d_out;

    const int* srcp = ei;
    const int* dstp = ei + N_EDGES;

    // workspace: dinv [N] | S [2N] | pooled [H]  (~600 KB total)
    float* dinv   = (float*)d_ws;
    float* S      = dinv + N_NODES;
    float* pooled = S + 2 * (size_t)N_NODES;

    hipMemsetAsync(dinv, 0, (3 * (size_t)N_NODES + HIDDEN) * sizeof(float), stream);

    const int EB = (N_EDGES + 255) / 256;
    const int NB = (N_NODES + 255) / 256;
    deg_kernel<<<EB, 256, 0, stream>>>(dstp, dinv, N_EDGES);
    dinv_kernel<<<NB, 256, 0, stream>>>(dinv, N_NODES);
    scatter2_kernel<<<EB, 256, 0, stream>>>(srcp, dstp, (const float2*)nf, dinv, S, N_EDGES);
    ln_pool_kernel<<<256, 256, 0, stream>>>((const float2*)nf, Wg, dinv, S, bg, gamma, beta, pooled, N_NODES);
    mlp_kernel<<<1, 256, 0, stream>>>(pooled, Wh, bh, Wo, bo, out);
}

// Round 3
// 98.184 us; speedup vs baseline: 28.5517x; 1.8952x over previous
//
#include <hip/hip_runtime.h>
#include <math.h>

#define N_NODES 50000
#define N_EDGES 800000
#define HIDDEN  256
#define OUT_DIM 10
#define LN_EPS  1e-5f

#define NP    8                    // node partitions
#define PART  (N_NODES / NP)       // 6250 nodes per partition
#define ES    32                   // edge slices
#define EPSE  (N_EDGES / ES)       // 25000 edges per slice

// --------------------------------------------------- privatized histogram ----
// Block (slice, part): LDS histogram of its node range over its edge slice.
// No global atomics; partials flushed with plain coalesced stores.
__global__ __launch_bounds__(1024) void hist_kernel(const int* __restrict__ dst,
                                                    unsigned* __restrict__ degp) {
    __shared__ unsigned hist[PART];          // 25 KB
    const int tid = threadIdx.x;
    for (int i = tid; i < PART; i += 1024) hist[i] = 0u;
    __syncthreads();

    const int base = blockIdx.y * PART;
    const int e0 = blockIdx.x * EPSE, e1 = e0 + EPSE;
    for (int e = e0 + tid; e < e1; e += 1024) {
        const unsigned r = (unsigned)(dst[e] - base);
        if (r < PART) atomicAdd(&hist[r], 1u);
    }
    __syncthreads();

    unsigned* out = degp + (size_t)blockIdx.x * N_NODES + base;
    for (int i = tid; i < PART; i += 1024) out[i] = hist[i];
}

// deg partials -> dinv[n] = rsqrt(deg+1), y[n] = dinv[n] * x[n]
__global__ __launch_bounds__(256) void dinv_y_kernel(const unsigned* __restrict__ degp,
                                                     const float2* __restrict__ nf,
                                                     float* __restrict__ dinv,
                                                     float2* __restrict__ y) {
    const int t = blockIdx.x * 256 + threadIdx.x;
    if (t >= N_NODES) return;
    unsigned deg = 0;
    #pragma unroll
    for (int s = 0; s < ES; ++s) deg += degp[(size_t)s * N_NODES + t];
    const float di = rsqrtf((float)deg + 1.0f);
    dinv[t] = di;
    const float2 x = nf[t];
    y[t] = make_float2(di * x.x, di * x.y);
}

// ------------------------------------------------ privatized edge scatter ----
// T[d] = sum_{e: dst=d} y[src_e]   (dinv[d] applied later in ln_pool)
__global__ __launch_bounds__(1024) void scatterp_kernel(const int* __restrict__ src,
                                                        const int* __restrict__ dst,
                                                        const float2* __restrict__ y,
                                                        float* __restrict__ Tpart) {
    __shared__ float T[2 * PART];            // 50 KB
    const int tid = threadIdx.x;
    for (int i = tid; i < 2 * PART; i += 1024) T[i] = 0.f;
    __syncthreads();

    const int base = blockIdx.y * PART;
    const int e0 = blockIdx.x * EPSE, e1 = e0 + EPSE;
    for (int e = e0 + tid; e < e1; e += 1024) {
        const unsigned r = (unsigned)(dst[e] - base);
        if (r < PART) {
            const float2 ys = y[src[e]];
            atomicAdd(&T[2 * r],     ys.x);
            atomicAdd(&T[2 * r + 1], ys.y);
        }
    }
    __syncthreads();

    float* out = Tpart + (size_t)blockIdx.x * (2 * N_NODES) + 2 * base;
    for (int i = tid; i < 2 * PART; i += 1024) out[i] = T[i];
}

__global__ __launch_bounds__(256) void reduceT_kernel(const float* __restrict__ Tpart,
                                                      float* __restrict__ T) {
    const int t = blockIdx.x * 256 + threadIdx.x;
    if (t >= 2 * N_NODES) return;
    float s = 0.f;
    #pragma unroll
    for (int p = 0; p < ES; ++p) s += Tpart[(size_t)p * (2 * N_NODES) + t];
    T[t] = s;
}

// --------------------------------------- GCN expand + relu + LN + pool ----
// Wave-per-node; s[n] = dinv[n] * (T[n] + y[n])  (y term = self-loop)
__global__ __launch_bounds__(256) void ln_pool_kernel(const float2* __restrict__ T2,
                                                      const float2* __restrict__ y,
                                                      const float* __restrict__ dinv,
                                                      const float* __restrict__ Wg,
                                                      const float* __restrict__ bg,
                                                      const float* __restrict__ gamma,
                                                      const float* __restrict__ beta,
                                                      float* __restrict__ pooled, int N) {
    const int tid  = threadIdx.x;
    const int lane = tid & 63;
    const int wv   = tid >> 6;
    const int gw   = (blockIdx.x * blockDim.x + tid) >> 6;
    const int nw   = (gridDim.x * blockDim.x) >> 6;

    const float4 w0  = *reinterpret_cast<const float4*>(&Wg[lane * 4]);
    const float4 w1  = *reinterpret_cast<const float4*>(&Wg[HIDDEN + lane * 4]);
    const float4 bgv = *reinterpret_cast<const float4*>(&bg[lane * 4]);
    const float4 gv  = *reinterpret_cast<const float4*>(&gamma[lane * 4]);
    const float4 bv  = *reinterpret_cast<const float4*>(&beta[lane * 4]);

    float a0 = 0.f, a1 = 0.f, a2 = 0.f, a3 = 0.f;

    for (int n = gw; n < N; n += nw) {
        const float di = dinv[n];
        const float2 t = T2[n];
        const float2 yn = y[n];
        const float s0 = di * (t.x + yn.x);
        const float s1 = di * (t.y + yn.y);

        float v0 = fmaxf(fmaf(s1, w1.x, fmaf(s0, w0.x, bgv.x)), 0.f);
        float v1 = fmaxf(fmaf(s1, w1.y, fmaf(s0, w0.y, bgv.y)), 0.f);
        float v2 = fmaxf(fmaf(s1, w1.z, fmaf(s0, w0.z, bgv.z)), 0.f);
        float v3 = fmaxf(fmaf(s1, w1.w, fmaf(s0, w0.w, bgv.w)), 0.f);

        float sum = v0 + v1 + v2 + v3;
        float sq  = v0 * v0 + v1 * v1 + v2 * v2 + v3 * v3;
        #pragma unroll
        for (int o = 1; o < 64; o <<= 1) {
            sum += __shfl_xor(sum, o, 64);
            sq  += __shfl_xor(sq,  o, 64);
        }
        const float mu   = sum * (1.0f / HIDDEN);
        const float var  = sq * (1.0f / HIDDEN) - mu * mu;
        const float rstd = rsqrtf(var + LN_EPS);

        a0 += (v0 - mu) * rstd * gv.x + bv.x;
        a1 += (v1 - mu) * rstd * gv.y + bv.y;
        a2 += (v2 - mu) * rstd * gv.z + bv.z;
        a3 += (v3 - mu) * rstd * gv.w + bv.w;
    }

    __shared__ float lds[4][HIDDEN];
    lds[wv][lane * 4 + 0] = a0;
    lds[wv][lane * 4 + 1] = a1;
    lds[wv][lane * 4 + 2] = a2;
    lds[wv][lane * 4 + 3] = a3;
    __syncthreads();
    const float tsum = lds[0][tid] + lds[1][tid] + lds[2][tid] + lds[3][tid];
    atomicAdd(&pooled[tid], tsum);
}

// ------------------------------------------------------------- MLP head ----
__global__ __launch_bounds__(256) void mlp_kernel(const float* __restrict__ pooled,
                                                  const float* __restrict__ Wh,
                                                  const float* __restrict__ bh,
                                                  const float* __restrict__ Wo,
                                                  const float* __restrict__ bo,
                                                  float* __restrict__ out) {
    __shared__ float p[HIDDEN], z[HIDDEN], logits[OUT_DIM];
    const int j = threadIdx.x;
    p[j] = pooled[j];
    __syncthreads();

    float s = bh[j];
    for (int k = 0; k < HIDDEN; ++k) s += p[k] * Wh[k * HIDDEN + j];
    z[j] = fmaxf(s, 0.0f);
    __syncthreads();

    if (j < OUT_DIM) {
        float t = bo[j];
        for (int k = 0; k < HIDDEN; ++k) t += z[k] * Wo[k * OUT_DIM + j];
        logits[j] = t;
    }
    __syncthreads();

    if (j == 0) {
        float m = logits[0];
        for (int k = 1; k < OUT_DIM; ++k) m = fmaxf(m, logits[k]);
        float sum = 0.0f;
        for (int k = 0; k < OUT_DIM; ++k) sum += expf(logits[k] - m);
        const float lse = m + logf(sum);
        for (int k = 0; k < OUT_DIM; ++k) out[k] = logits[k] - lse;
    }
}

// ---------------------------------------------------------------- launch ----
extern "C" void kernel_launch(void* const* d_in, const int* in_sizes, int n_in,
                              void* d_out, int out_size, void* d_ws, size_t ws_size,
                              hipStream_t stream) {
    const float* nf    = (const float*)d_in[0];   // [N, 2]
    const int*   ei    = (const int*)  d_in[1];   // [2, E] int32
    const float* Wg    = (const float*)d_in[2];
    const float* bg    = (const float*)d_in[3];
    const float* gamma = (const float*)d_in[4];
    const float* beta  = (const float*)d_in[5];
    const float* Wh    = (const float*)d_in[6];
    const float* bh    = (const float*)d_in[7];
    const float* Wo    = (const float*)d_in[8];
    const float* bo    = (const float*)d_in[9];
    float* out = (float*)d_out;

    const int* srcp = ei;
    const int* dstp = ei + N_EDGES;

    // workspace layout (floats/u32, all 4B):
    // degp [ES*N] u32 | Tpart [ES*2N] f32 | dinv [N] | y [2N] | T [2N] | pooled [H]
    unsigned* degp = (unsigned*)d_ws;
    float* Tpart   = (float*)d_ws + (size_t)ES * N_NODES;
    float* dinv    = Tpart + (size_t)ES * 2 * N_NODES;
    float* y       = dinv + N_NODES;
    float* T       = y + 2 * N_NODES;
    float* pooled  = T + 2 * N_NODES;

    hipMemsetAsync(pooled, 0, HIDDEN * sizeof(float), stream);

    dim3 pg(ES, NP);
    hist_kernel<<<pg, 1024, 0, stream>>>(dstp, degp);
    dinv_y_kernel<<<(N_NODES + 255) / 256, 256, 0, stream>>>(degp, (const float2*)nf, dinv, (float2*)y);
    scatterp_kernel<<<pg, 1024, 0, stream>>>(srcp, dstp, (const float2*)y, Tpart);
    reduceT_kernel<<<(2 * N_NODES + 255) / 256, 256, 0, stream>>>(Tpart, T);
    ln_pool_kernel<<<256, 256, 0, stream>>>((const float2*)T, (const float2*)y, dinv, Wg, bg, gamma, beta, pooled, N_NODES);
    mlp_kernel<<<1, 256, 0, stream>>>(pooled, Wh, bh, Wo, bo, out);
}